// Round 6
// baseline (4912.043 us; speedup 1.0000x reference)
//
#include <hip/hip_runtime.h>
#include <hip/hip_bf16.h>
#include <math.h>

static constexpr int BB = 32;
static constexpr int TT = 256;
static constexpr int EE = 512;
static constexpr int HH = 512;
static constexpr int GG = 2048;  // 4H

static constexpr int HS = 36;  // h_lds row stride (32 b + 4 pad) -> sigma=9 (odd)

using u16 = unsigned short;

__device__ __forceinline__ float bf2f(u16 u) {
    return __uint_as_float(((unsigned int)u) << 16);
}
__device__ __forceinline__ u16 f2bf(float f) {
    unsigned int u = __float_as_uint(f);
    unsigned int r = 0x7FFFu + ((u >> 16) & 1u);
    return (u16)((u + r) >> 16);
}
__device__ __forceinline__ float sigm(float x) {
    return 1.0f / (1.0f + expf(-x));
}

// ---- coherence-point (L3) accessors: sc0 sc1 = system-scope, bypass L1/L2.
// All cross-WG mutable data goes through these -> NO wbl2/inv ever needed in
// the recurrent loop -> read-only xg/Whh stay L2-cached across all 256 steps.
__device__ __forceinline__ float4 ld_b128_sc(const float4* p) {
    float4 v;
    asm volatile("global_load_dwordx4 %0, %1, off sc0 sc1" : "=v"(v) : "v"(p));
    return v;
}
__device__ __forceinline__ void st_b32_sc(float* p, float v) {
    asm volatile("global_store_dword %0, %1, off sc0 sc1" :: "v"(p), "v"(v) : "memory");
}

template<bool F32>
__device__ __forceinline__ float ldw(const void* p, size_t i) {
    if constexpr (F32) return ((const float*)p)[i];
    else               return bf2f(((const u16*)p)[i]);
}
template<bool F32>
__device__ __forceinline__ float4 ld4(const void* p, size_t i) {  // i % 4 == 0
    if constexpr (F32) {
        return *(const float4*)((const float*)p + i);
    } else {
        ushort4 v = *(const ushort4*)((const u16*)p + i);
        return make_float4(bf2f(v.x), bf2f(v.y), bf2f(v.z), bf2f(v.w));
    }
}

// ---------------- init: zero state, zero barrier, detect dtype ----------------
__global__ void init_state(const u16* __restrict__ bih_probe,
                           float* __restrict__ h_st, float* __restrict__ c_st,
                           int* __restrict__ bar, int* __restrict__ flag) {
    size_t i = (size_t)blockIdx.x * blockDim.x + threadIdx.x;
    size_t stride = (size_t)gridDim.x * blockDim.x;
    for (size_t j = i; j < (size_t)2*2*BB*HH; j += stride) h_st[j] = 0.0f;
    for (size_t j = i; j < (size_t)2*BB*HH;   j += stride) c_st[j] = 0.0f;
    for (size_t j = i; j < 1024;              j += stride) bar[j] = 0;
    if (blockIdx.x == 0 && threadIdx.x == 0) {
        int f = 0;
        for (int k = 0; k < 2048; ++k) {
            int e = (bih_probe[k] >> 7) & 0xFF;
            if (e >= 127) f = 1;
        }
        *flag = f;
    }
}

// ---------------- phase 1: xg = x @ Wih + bih + bhh ----------------
// Output layout: xg[d][t][nblk(128)][c0(16)][b(32)] fp32, c0 = g*4 + nl,
// col = g*512 + nblk*4 + nl. Per rec-WG per-step slice = contiguous 2 KB.
template<bool F32>
__device__ __forceinline__ void xg_body(
    const void* __restrict__ x, const void* __restrict__ Wih,
    const void* __restrict__ bih, const void* __restrict__ bhh,
    float* __restrict__ xgp, int d, int mt, int nt, float* b_lds)
{
    const int tid = threadIdx.x;
    const int tn = tid & 15;
    const int tm = tid >> 4;
    const int m0 = mt * 64;
    const int n0 = nt * 64;

    size_t a_off[4];
    #pragma unroll
    for (int i = 0; i < 4; ++i) {
        const int m = m0 + 4*tm + i;
        const int t = m >> 5, b = m & 31;
        const int t_src = d ? (TT - 1 - t) : t;
        a_off[i] = ((size_t)b * TT + t_src) * EE;
    }

    float acc[4][4];
    #pragma unroll
    for (int i = 0; i < 4; ++i)
        #pragma unroll
        for (int j = 0; j < 4; ++j) acc[i][j] = 0.0f;

    const int kr = tid >> 2;
    const int nc = (tid & 3) * 16;

    for (int k0 = 0; k0 < EE; k0 += 64) {
        __syncthreads();
        #pragma unroll 4
        for (int e = 0; e < 16; ++e)
            b_lds[kr*64 + nc + e] = ldw<F32>(Wih, (size_t)(k0 + kr)*GG + n0 + nc + e);
        __syncthreads();

        #pragma unroll 2
        for (int kk = 0; kk < 64; kk += 4) {
            float4 av[4];
            #pragma unroll
            for (int i = 0; i < 4; ++i) av[i] = ld4<F32>(x, a_off[i] + k0 + kk);
            #pragma unroll
            for (int j = 0; j < 4; ++j) {
                const float4 bv = *(const float4*)&b_lds[(kk + j)*64 + 4*tn];
                #pragma unroll
                for (int i = 0; i < 4; ++i) {
                    const float a = (j == 0) ? av[i].x : (j == 1) ? av[i].y
                                  : (j == 2) ? av[i].z : av[i].w;
                    acc[i][0] += a * bv.x; acc[i][1] += a * bv.y;
                    acc[i][2] += a * bv.z; acc[i][3] += a * bv.w;
                }
            }
        }
    }

    const int mbase = m0 + 4*tm;
    const int tt = mbase >> 5, bb = mbase & 31;   // 4 rows share t; b quad-aligned
    #pragma unroll
    for (int j = 0; j < 4; ++j) {
        const int col  = n0 + 4*tn + j;
        const float bs = ldw<F32>(bih, col) + ldw<F32>(bhh, col);
        const int g    = col >> 9;
        const int nblk = (col & 511) >> 2;
        const int nl   = col & 3;
        const size_t idx = (((size_t)d*TT + tt)*65536)
                         + (size_t)nblk*512 + (size_t)(g*4 + nl)*32 + bb;
        float4 v = make_float4(acc[0][j] + bs, acc[1][j] + bs,
                               acc[2][j] + bs, acc[3][j] + bs);
        *(float4*)&xgp[idx] = v;
    }
}

__global__ __launch_bounds__(256) void xg_gemm(
    const void* __restrict__ x,
    const void* __restrict__ WihF, const void* __restrict__ bihF, const void* __restrict__ bhhF,
    const void* __restrict__ WihB, const void* __restrict__ bihB, const void* __restrict__ bhhB,
    float* __restrict__ xgp, const int* __restrict__ flag)
{
    __shared__ float b_lds[64 * 64];
    const int bid = blockIdx.x;
    const int d  = bid >> 12;
    const int r  = bid & 4095;
    const int mt = r >> 5;
    const int nt = r & 31;
    const void* Wih = d ? WihB : WihF;
    const void* bih = d ? bihB : bihF;
    const void* bhh = d ? bhhB : bhhF;
    if (*flag) xg_body<true >(x, Wih, bih, bhh, xgp, d, mt, nt, b_lds);
    else       xg_body<false>(x, Wih, bih, bhh, xgp, d, mt, nt, b_lds);
}

// ---------------- phase 2: persistent recurrent kernel ----------------
// Grid: 256 WGs = dir(2) x nblk(128); 1 WG/CU.
// h stored TRANSPOSED in ws: hT[d][parity][k(512)][b(32)] fp32.
//
// Cross-WG protocol: round-1 verbatim (best measured; sc0/sc1 h exchange,
// relaxed 2-level atomic tree, tid0 aggregate poll).
// Round-6 change (ONLY): Whh lives in REGISTERS, not LDS. Each thread's
// weight working set is exactly w4[kk] = Whh[kk*8+kg][cg*512+nblk*4 .. +3]
// (64 x float4 = 256 VGPR), loaded ONCE before the t-loop (L2-cached,
// one-time). MAC becomes 1 ds_read_b128 (hv) + 16 FMA per kk -> halves the
// per-step LDS pipe load (wv reads gone) and kills wv-side bank conflicts.
// wT_lds (40 KB) deleted -> LDS 74 KB.
__device__ __forceinline__ void grid_bar_dir(int* __restrict__ bard, int wgl, int target) {
    asm volatile("s_waitcnt vmcnt(0)" ::: "memory");  // per-wave release: sc stores acked at L3
    __syncthreads();
    if (threadIdx.x == 0) {
        int v = __hip_atomic_fetch_add(&bard[32 + (wgl >> 4) * 32], 1,
                                       __ATOMIC_RELAXED, __HIP_MEMORY_SCOPE_AGENT);
        if ((v & 15) == 15)
            __hip_atomic_fetch_add(&bard[0], 1, __ATOMIC_RELAXED, __HIP_MEMORY_SCOPE_AGENT);
        while (__hip_atomic_load(&bard[0], __ATOMIC_RELAXED, __HIP_MEMORY_SCOPE_AGENT) < target)
            __builtin_amdgcn_s_sleep(1);
    }
    __syncthreads();
}

template<bool F32>
__device__ __forceinline__ void rec_body(
    const void* __restrict__ Whh,
    const float* __restrict__ xgp,   // [2][256][128][16][32] fp32 (biases folded)
    float* __restrict__ hT,          // [2 dir][2 parity][512 k][32 b] fp32
    int* __restrict__ bar,
    void* __restrict__ out, int d, int nblk, int wgl,
    float* __restrict__ h_lds,       // [512][HS]
    float* __restrict__ gbuf)        // [512]
{
    const int tid = threadIdx.x;
    const int cg = tid >> 6;          // wave id = GATE (4 cols each)
    const int bg = (tid >> 3) & 7;    // 4 batches each
    const int kg = tid & 7;           // k-split (lane bits 0..2), interleaved

    // ---- preload Whh fragment into registers (constant across all steps):
    //      w4[kk] = Whh[kk*8+kg][cg*512 + nblk*4 + (0..3)] ----
    float4 w4[64];
    {
        const size_t cbase = (size_t)cg*512 + (size_t)nblk*4;
        #pragma unroll
        for (int kk = 0; kk < 64; ++kk)
            w4[kk] = ld4<F32>(Whh, (size_t)(kk*8 + kg)*GG + cbase);
    }

    int* bard = bar + d*512;          // d=0 -> bar[0..256], d=1 -> bar[512..768]
    float cr = 0.0f;                  // cell state (gate threads tid<128)
    const int gnl = tid >> 5;         // gate thread: nl (valid when tid<128)
    const int gb  = tid & 31;         // gate thread: b

    const float* hp = h_lds + kg*HS + bg*4;

    __syncthreads();

    for (int t = 0; t < TT; ++t) {
        const int parity = t & 1;
        const float4* hprev4 = (const float4*)(hT + (size_t)(d*2 + (parity ^ 1)) * 16384);
        float*        hnext  = hT + (size_t)(d*2 + parity) * 16384;

        // ---- prefetch xg (constant data; plain cached loads, stays in L2) ----
        float xgv[4] = {0.f, 0.f, 0.f, 0.f};
        if (tid < 128) {
            const float* xgs = xgp + (((size_t)d*TT + t)*65536) + (size_t)nblk*512;
            #pragma unroll
            for (int g = 0; g < 4; ++g)
                xgv[g] = xgs[(g*4 + gnl)*32 + gb];
        }

        // ---- stage hT -> LDS via sc loads, single drain (round-1) ----
        float4 hstg[16];
        #pragma unroll
        for (int i = 0; i < 16; ++i)
            hstg[i] = ld_b128_sc(hprev4 + i*256 + tid);
        asm volatile("s_waitcnt vmcnt(0)" ::: "memory");
        __builtin_amdgcn_sched_barrier(0);
        #pragma unroll
        for (int i = 0; i < 16; ++i) {
            const int idx = i*256 + tid;
            const int k  = idx >> 3;
            const int b4 = idx & 7;
            *(float4*)&h_lds[k*HS + b4*4] = hstg[i];
        }
        __syncthreads();

        // ---- MAC: acc[ci][bi], k = kk*8 + kg; weights from REGISTERS ----
        float acc[4][4];
        #pragma unroll
        for (int i = 0; i < 4; ++i)
            #pragma unroll
            for (int j = 0; j < 4; ++j) acc[i][j] = 0.0f;
        #pragma unroll
        for (int kk = 0; kk < 64; ++kk) {
            const float4 hv = *(const float4*)(hp + kk*(8*HS));
            const float4 wv = w4[kk];
            acc[0][0] += wv.x*hv.x; acc[0][1] += wv.x*hv.y; acc[0][2] += wv.x*hv.z; acc[0][3] += wv.x*hv.w;
            acc[1][0] += wv.y*hv.x; acc[1][1] += wv.y*hv.y; acc[1][2] += wv.y*hv.z; acc[1][3] += wv.y*hv.w;
            acc[2][0] += wv.z*hv.x; acc[2][1] += wv.z*hv.y; acc[2][2] += wv.z*hv.z; acc[2][3] += wv.z*hv.w;
            acc[3][0] += wv.w*hv.x; acc[3][1] += wv.w*hv.y; acc[3][2] += wv.w*hv.z; acc[3][3] += wv.w*hv.w;
        }

        // ---- reduce k-partials across kg (lane bits 0..2) ----
        #pragma unroll
        for (int i = 0; i < 4; ++i)
            #pragma unroll
            for (int j = 0; j < 4; ++j) {
                float v = acc[i][j];
                v += __shfl_xor(v, 1);
                v += __shfl_xor(v, 2);
                v += __shfl_xor(v, 4);
                acc[i][j] = v;
            }
        if (kg < 4) {
            const int ci = kg;
            *(float4*)&gbuf[(cg*4 + ci)*32 + bg*4] =
                make_float4(acc[ci][0], acc[ci][1], acc[ci][2], acc[ci][3]);
        }
        __syncthreads();

        // ---- gate combine: 128 threads, one (nl, b) each ----
        if (tid < 128) {
            const int nl = gnl;
            const int b  = gb;
            const float gi = gbuf[(0*4 + nl)*32 + b] + xgv[0];
            const float gf = gbuf[(1*4 + nl)*32 + b] + xgv[1];
            const float gc = gbuf[(2*4 + nl)*32 + b] + xgv[2];
            const float go = gbuf[(3*4 + nl)*32 + b] + xgv[3];
            const float cn = sigm(gf)*cr + sigm(gi)*tanhf(gc);
            cr = cn;
            const float hv = sigm(go)*tanhf(cn);
            const int ng = nblk*4 + nl;
            st_b32_sc(hnext + (size_t)ng*32 + b, hv);             // write-through to L3
            const size_t oi = ((size_t)b*TT + t)*(2*HH) + (size_t)d*HH + ng;
            if constexpr (F32) ((float*)out)[oi] = hv;
            else               ((u16*)out)[oi]   = f2bf(hv);
        }
        grid_bar_dir(bard, wgl, 8 * (t + 1));
    }
}

__global__ __launch_bounds__(256, 1) void lstm_rec(
    const void* __restrict__ WhhF, const void* __restrict__ WhhB,
    const float* __restrict__ xgp, float* __restrict__ hT,
    int* __restrict__ bar, const int* __restrict__ flag,
    void* __restrict__ out)
{
    __shared__ float h_lds[512 * HS];    // 72 KB
    __shared__ float gbuf[512];          //  2 KB
    const int wg   = blockIdx.x;
    const int d    = wg >> 7;
    const int nblk = wg & 127;
    const void* Whh = d ? WhhB : WhhF;
    if (*flag) rec_body<true >(Whh, xgp, hT, bar, out, d, nblk, wg & 127, h_lds, gbuf);
    else       rec_body<false>(Whh, xgp, hT, bar, out, d, nblk, wg & 127, h_lds, gbuf);
}

// ---------------- fallback: proven round-3/4 per-step kernel ----------------
template<bool F32>
__device__ __forceinline__ void step_body(
    const void* __restrict__ x,
    const void* __restrict__ Wih, const void* __restrict__ bih,
    const void* __restrict__ Whh, const void* __restrict__ bhh,
    const float* __restrict__ h_prev, float* __restrict__ h_next,
    float* __restrict__ c_st, void* __restrict__ out,
    int d, int nblk, int t, int t_src, float* __restrict__ gbuf)
{
    const int tid = threadIdx.x;
    const int c0  = tid & 15;
    const int g   = c0 >> 2;
    const int nl  = c0 & 3;
    const int bq  = tid >> 4;
    const int col = g*512 + nblk*4 + nl;
    const int b0 = bq*2, b1 = b0 + 1;

    float p00=0.f,p01=0.f,p02=0.f,p03=0.f;
    float p10=0.f,p11=0.f,p12=0.f,p13=0.f;
    {
        const size_t xo0 = ((size_t)b0*TT + t_src) * EE;
        const size_t xo1 = ((size_t)b1*TT + t_src) * EE;
        #pragma unroll 4
        for (int k = 0; k < EE; k += 4) {
            const size_t wi = (size_t)k*GG + col;
            float w0 = ldw<F32>(Wih, wi);
            float w1 = ldw<F32>(Wih, wi +   (size_t)GG);
            float w2 = ldw<F32>(Wih, wi + 2*(size_t)GG);
            float w3 = ldw<F32>(Wih, wi + 3*(size_t)GG);
            float4 a0 = ld4<F32>(x, xo0 + k);
            float4 a1 = ld4<F32>(x, xo1 + k);
            p00 += w0*a0.x; p01 += w1*a0.y; p02 += w2*a0.z; p03 += w3*a0.w;
            p10 += w0*a1.x; p11 += w1*a1.y; p12 += w2*a1.z; p13 += w3*a1.w;
        }
    }
    {
        const float* hr0 = h_prev + (size_t)b0*HH;
        const float* hr1 = h_prev + (size_t)b1*HH;
        #pragma unroll 4
        for (int k = 0; k < HH; k += 4) {
            const size_t wi = (size_t)k*GG + col;
            float w0 = ldw<F32>(Whh, wi);
            float w1 = ldw<F32>(Whh, wi +   (size_t)GG);
            float w2 = ldw<F32>(Whh, wi + 2*(size_t)GG);
            float w3 = ldw<F32>(Whh, wi + 3*(size_t)GG);
            float4 v0 = *(const float4*)(hr0 + k);
            float4 v1 = *(const float4*)(hr1 + k);
            p00 += w0*v0.x; p01 += w1*v0.y; p02 += w2*v0.z; p03 += w3*v0.w;
            p10 += w0*v1.x; p11 += w1*v1.y; p12 += w2*v1.z; p13 += w3*v1.w;
        }
    }
    const float bias = ldw<F32>(bih, col) + ldw<F32>(bhh, col);
    gbuf[tid*2 + 0] = p00 + p01 + p02 + p03 + bias;
    gbuf[tid*2 + 1] = p10 + p11 + p12 + p13 + bias;
    __syncthreads();
    if (c0 < 4) {
        const int nlc = c0;
        const int ng  = nblk*4 + nlc;
        #pragma unroll
        for (int bi = 0; bi < 2; ++bi) {
            const int b = bq*2 + bi;
            const float gi = gbuf[(bq*16 + 0  + nlc)*2 + bi];
            const float gf = gbuf[(bq*16 + 4  + nlc)*2 + bi];
            const float gc = gbuf[(bq*16 + 8  + nlc)*2 + bi];
            const float go = gbuf[(bq*16 + 12 + nlc)*2 + bi];
            const size_t ci = (size_t)b*HH + ng;
            const float cp = c_st[ci];
            const float cn = sigm(gf)*cp + sigm(gi)*tanhf(gc);
            c_st[ci] = cn;
            const float hv = sigm(go)*tanhf(cn);
            h_next[ci] = hv;
            const size_t oi = ((size_t)b*TT + t)*(2*HH) + (size_t)d*HH + ng;
            if constexpr (F32) ((float*)out)[oi] = hv;
            else               ((u16*)out)[oi]   = f2bf(hv);
        }
    }
}

__global__ __launch_bounds__(256) void lstm_step(
    const void* __restrict__ x,
    const void* __restrict__ WihF, const void* __restrict__ bihF,
    const void* __restrict__ WhhF, const void* __restrict__ bhhF,
    const void* __restrict__ WihB, const void* __restrict__ bihB,
    const void* __restrict__ WhhB, const void* __restrict__ bhhB,
    float* __restrict__ h_buf, float* __restrict__ c_buf,
    const int* __restrict__ flag, void* __restrict__ out, int t)
{
    __shared__ float gbuf[512];
    const int bid  = blockIdx.x;
    const int d    = bid >> 7;
    const int nblk = bid & 127;
    const void* Wih = d ? WihB : WihF;
    const void* Whh = d ? WhhB : WhhF;
    const void* bih = d ? bihB : bihF;
    const void* bhh = d ? bhhB : bhhF;
    const int t_src  = d ? (TT - 1 - t) : t;
    const int parity = t & 1;
    const float* h_prev = h_buf + ((size_t)(d*2 + (parity ^ 1))) * BB * HH;
    float*       h_next = h_buf + ((size_t)(d*2 + parity)) * BB * HH;
    float*       c_st   = c_buf + (size_t)d * BB * HH;
    if (*flag) step_body<true >(x, Wih, bih, Whh, bhh, h_prev, h_next, c_st, out, d, nblk, t, t_src, gbuf);
    else       step_body<false>(x, Wih, bih, Whh, bhh, h_prev, h_next, c_st, out, d, nblk, t, t_src, gbuf);
}

// ---------------- host ----------------
extern "C" void kernel_launch(void* const* d_in, const int* in_sizes, int n_in,
                              void* d_out, int out_size, void* d_ws, size_t ws_size,
                              hipStream_t stream) {
    const void* x    = d_in[0];
    const void* WihF = d_in[1];
    const void* bihF = d_in[2];
    const void* WhhF = d_in[3];
    const void* bhhF = d_in[4];
    const void* WihB = d_in[5];
    const void* bihB = d_in[6];
    const void* WhhB = d_in[7];
    const void* bhhB = d_in[8];

    float* ws = (float*)d_ws;

    // layout (floats): xg[33554432] | h[65536] | c[32768] | bar[1024 ints] | flag
    const size_t off_xg = 0;
    const size_t off_h  = (size_t)2*TT*BB*GG;            // 33554432
    const size_t off_c  = off_h + (size_t)2*2*BB*HH;     // + 65536
    const size_t off_b  = off_c + (size_t)2*BB*HH;       // + 32768
    const size_t off_f  = off_b + 1024;
    const size_t need_bytes = (off_f + 16) * sizeof(float);

    if (ws_size >= need_bytes) {
        float* xgp  = ws + off_xg;
        float* hT   = ws + off_h;     // transposed: [2][2][512 k][32 b]
        float* cbuf = ws + off_c;     // unused by fast path (zeroed anyway)
        int*   bar  = (int*)(ws + off_b);
        int*   flag = (int*)(ws + off_f);

        init_state<<<64, 256, 0, stream>>>((const u16*)bihF, hT, cbuf, bar, flag);
        xg_gemm<<<8192, 256, 0, stream>>>(x, WihF, bihF, bhhF, WihB, bihB, bhhB, xgp, flag);
        lstm_rec<<<256, 256, 0, stream>>>(WhhF, WhhB, xgp, hT, bar, flag, d_out);
    } else {
        float* h_buf = ws;
        float* c_buf = ws + (size_t)2*2*BB*HH;
        int*   bar   = (int*)(c_buf + (size_t)2*BB*HH);
        int*   flag  = (int*)(bar + 1024);
        init_state<<<64, 256, 0, stream>>>((const u16*)bihF, h_buf, c_buf, bar, flag);
        for (int t = 0; t < TT; ++t) {
            lstm_step<<<256, 256, 0, stream>>>(x, WihF, bihF, WhhF, bhhF,
                                               WihB, bihB, WhhB, bhhB,
                                               h_buf, c_buf, flag, d_out, t);
        }
    }
}

// Round 7
// 2740.069 us; speedup vs baseline: 1.7927x; 1.7927x over previous
//
#include <hip/hip_runtime.h>
#include <hip/hip_bf16.h>
#include <math.h>

static constexpr int BB = 32;
static constexpr int TT = 256;
static constexpr int EE = 512;
static constexpr int HH = 512;
static constexpr int GG = 2048;  // 4H

static constexpr int WS = 20;  // wT_lds row stride (16 cols + 4 pad) -> sigma=5 (odd)
static constexpr int HS = 36;  // h_lds  row stride (32 b   + 4 pad) -> sigma=9 (odd)

using u16 = unsigned short;

__device__ __forceinline__ float bf2f(u16 u) {
    return __uint_as_float(((unsigned int)u) << 16);
}
__device__ __forceinline__ u16 f2bf(float f) {
    unsigned int u = __float_as_uint(f);
    unsigned int r = 0x7FFFu + ((u >> 16) & 1u);
    return (u16)((u + r) >> 16);
}
__device__ __forceinline__ float sigm(float x) {
    return 1.0f / (1.0f + expf(-x));
}

// ---- coherence-point (L3) accessors: sc0 sc1 = system-scope, bypass L1/L2.
// All cross-WG mutable data goes through these -> NO wbl2/inv ever needed in
// the recurrent loop -> read-only xg/Whh stay L2-cached across all 256 steps.
__device__ __forceinline__ float4 ld_b128_sc(const float4* p) {
    float4 v;
    asm volatile("global_load_dwordx4 %0, %1, off sc0 sc1" : "=v"(v) : "v"(p));
    return v;
}
__device__ __forceinline__ void st_b32_sc(float* p, float v) {
    asm volatile("global_store_dword %0, %1, off sc0 sc1" :: "v"(p), "v"(v) : "memory");
}

template<bool F32>
__device__ __forceinline__ float ldw(const void* p, size_t i) {
    if constexpr (F32) return ((const float*)p)[i];
    else               return bf2f(((const u16*)p)[i]);
}
template<bool F32>
__device__ __forceinline__ float4 ld4(const void* p, size_t i) {  // i % 4 == 0
    if constexpr (F32) {
        return *(const float4*)((const float*)p + i);
    } else {
        ushort4 v = *(const ushort4*)((const u16*)p + i);
        return make_float4(bf2f(v.x), bf2f(v.y), bf2f(v.z), bf2f(v.w));
    }
}

// ---------------- init: zero state, zero barrier, detect dtype ----------------
__global__ void init_state(const u16* __restrict__ bih_probe,
                           float* __restrict__ h_st, float* __restrict__ c_st,
                           int* __restrict__ bar, int* __restrict__ flag) {
    size_t i = (size_t)blockIdx.x * blockDim.x + threadIdx.x;
    size_t stride = (size_t)gridDim.x * blockDim.x;
    for (size_t j = i; j < (size_t)2*2*BB*HH; j += stride) h_st[j] = 0.0f;
    for (size_t j = i; j < (size_t)2*BB*HH;   j += stride) c_st[j] = 0.0f;
    for (size_t j = i; j < 1024;              j += stride) bar[j] = 0;
    if (blockIdx.x == 0 && threadIdx.x == 0) {
        int f = 0;
        for (int k = 0; k < 2048; ++k) {
            int e = (bih_probe[k] >> 7) & 0xFF;
            if (e >= 127) f = 1;
        }
        *flag = f;
    }
}

// ---------------- phase 1: xg = x @ Wih + bih + bhh ----------------
// Output layout: xg[d][t][nblk(128)][c0(16)][b(32)] fp32, c0 = g*4 + nl,
// col = g*512 + nblk*4 + nl. Per rec-WG per-step slice = contiguous 2 KB.
template<bool F32>
__device__ __forceinline__ void xg_body(
    const void* __restrict__ x, const void* __restrict__ Wih,
    const void* __restrict__ bih, const void* __restrict__ bhh,
    float* __restrict__ xgp, int d, int mt, int nt, float* b_lds)
{
    const int tid = threadIdx.x;
    const int tn = tid & 15;
    const int tm = tid >> 4;
    const int m0 = mt * 64;
    const int n0 = nt * 64;

    size_t a_off[4];
    #pragma unroll
    for (int i = 0; i < 4; ++i) {
        const int m = m0 + 4*tm + i;
        const int t = m >> 5, b = m & 31;
        const int t_src = d ? (TT - 1 - t) : t;
        a_off[i] = ((size_t)b * TT + t_src) * EE;
    }

    float acc[4][4];
    #pragma unroll
    for (int i = 0; i < 4; ++i)
        #pragma unroll
        for (int j = 0; j < 4; ++j) acc[i][j] = 0.0f;

    const int kr = tid >> 2;
    const int nc = (tid & 3) * 16;

    for (int k0 = 0; k0 < EE; k0 += 64) {
        __syncthreads();
        #pragma unroll 4
        for (int e = 0; e < 16; ++e)
            b_lds[kr*64 + nc + e] = ldw<F32>(Wih, (size_t)(k0 + kr)*GG + n0 + nc + e);
        __syncthreads();

        #pragma unroll 2
        for (int kk = 0; kk < 64; kk += 4) {
            float4 av[4];
            #pragma unroll
            for (int i = 0; i < 4; ++i) av[i] = ld4<F32>(x, a_off[i] + k0 + kk);
            #pragma unroll
            for (int j = 0; j < 4; ++j) {
                const float4 bv = *(const float4*)&b_lds[(kk + j)*64 + 4*tn];
                #pragma unroll
                for (int i = 0; i < 4; ++i) {
                    const float a = (j == 0) ? av[i].x : (j == 1) ? av[i].y
                                  : (j == 2) ? av[i].z : av[i].w;
                    acc[i][0] += a * bv.x; acc[i][1] += a * bv.y;
                    acc[i][2] += a * bv.z; acc[i][3] += a * bv.w;
                }
            }
        }
    }

    const int mbase = m0 + 4*tm;
    const int tt = mbase >> 5, bb = mbase & 31;   // 4 rows share t; b quad-aligned
    #pragma unroll
    for (int j = 0; j < 4; ++j) {
        const int col  = n0 + 4*tn + j;
        const float bs = ldw<F32>(bih, col) + ldw<F32>(bhh, col);
        const int g    = col >> 9;
        const int nblk = (col & 511) >> 2;
        const int nl   = col & 3;
        const size_t idx = (((size_t)d*TT + tt)*65536)
                         + (size_t)nblk*512 + (size_t)(g*4 + nl)*32 + bb;
        float4 v = make_float4(acc[0][j] + bs, acc[1][j] + bs,
                               acc[2][j] + bs, acc[3][j] + bs);
        *(float4*)&xgp[idx] = v;
    }
}

__global__ __launch_bounds__(256) void xg_gemm(
    const void* __restrict__ x,
    const void* __restrict__ WihF, const void* __restrict__ bihF, const void* __restrict__ bhhF,
    const void* __restrict__ WihB, const void* __restrict__ bihB, const void* __restrict__ bhhB,
    float* __restrict__ xgp, const int* __restrict__ flag)
{
    __shared__ float b_lds[64 * 64];
    const int bid = blockIdx.x;
    const int d  = bid >> 12;
    const int r  = bid & 4095;
    const int mt = r >> 5;
    const int nt = r & 31;
    const void* Wih = d ? WihB : WihF;
    const void* bih = d ? bihB : bihF;
    const void* bhh = d ? bhhB : bhhF;
    if (*flag) xg_body<true >(x, Wih, bih, bhh, xgp, d, mt, nt, b_lds);
    else       xg_body<false>(x, Wih, bih, bhh, xgp, d, mt, nt, b_lds);
}

// ---------------- phase 2: persistent recurrent kernel ----------------
// Grid: 256 WGs = dir(2) x nblk(128); 1 WG/CU (~114 KB LDS).
// Round 7: 512 threads / 8 waves per WG (2 waves/SIMD) — same algorithm,
// k split 16 ways (kg = tid&15, 4-shuffle reduce). Pipe totals per CU are
// unchanged; the doubled TLP covers the serial latency terms (L3 staging
// drain, barrier chain) that 1-wave/SIMD exposed (Occupancy 12.4% in R1-R6).
// Thread map: cg = tid>>7 (gate quadrant, const per wave), bg = (tid>>4)&7
// (4 batches), kg = tid&15 (lane bits 0..3 -> shuffles in-wave).
// Bank-quad checks still pass: h quad (kg+bg)%8, w quad (5kg+cg)%8 -> 8
// distinct per 8-lane group for kg in 0..15.
//
// Cross-WG protocol: round-1 verbatim (best measured; sc0/sc1 h exchange,
// relaxed 2-level atomic tree, tid0 aggregate poll).
__device__ __forceinline__ void grid_bar_dir(int* __restrict__ bard, int wgl, int target) {
    asm volatile("s_waitcnt vmcnt(0)" ::: "memory");  // per-wave release: sc stores acked at L3
    __syncthreads();
    if (threadIdx.x == 0) {
        int v = __hip_atomic_fetch_add(&bard[32 + (wgl >> 4) * 32], 1,
                                       __ATOMIC_RELAXED, __HIP_MEMORY_SCOPE_AGENT);
        if ((v & 15) == 15)
            __hip_atomic_fetch_add(&bard[0], 1, __ATOMIC_RELAXED, __HIP_MEMORY_SCOPE_AGENT);
        while (__hip_atomic_load(&bard[0], __ATOMIC_RELAXED, __HIP_MEMORY_SCOPE_AGENT) < target)
            __builtin_amdgcn_s_sleep(1);
    }
    __syncthreads();
}

template<bool F32>
__device__ __forceinline__ void rec_body(
    const void* __restrict__ Whh,
    const float* __restrict__ xgp,   // [2][256][128][16][32] fp32 (biases folded)
    float* __restrict__ hT,          // [2 dir][2 parity][512 k][32 b] fp32
    int* __restrict__ bar,
    void* __restrict__ out, int d, int nblk, int wgl,
    float* __restrict__ wT_lds,      // [512][WS]
    float* __restrict__ h_lds,       // [512][HS]
    float* __restrict__ gbuf)        // [512]
{
    const int tid = threadIdx.x;
    const int cg = tid >> 7;          // gate quadrant (4 cols), const per wave
    const int bg = (tid >> 4) & 7;    // 4 batches each
    const int kg = tid & 15;          // k-split (lane bits 0..3), interleaved

    // ---- stage Whh transposed once: wT_lds[k*WS + ci] = Whh[k][col(ci)] ----
    {
        const int ci = tid & 15;
        const int cw = (ci >> 2)*512 + nblk*4 + (ci & 3);
        const int kb = (tid >> 4) * 16;   // 32 groups x 16 rows = 512
        #pragma unroll 4
        for (int k = kb; k < kb + 16; ++k)
            wT_lds[k*WS + ci] = ldw<F32>(Whh, (size_t)k*GG + cw);
    }

    int* bard = bar + d*512;          // d=0 -> bar[0..256], d=1 -> bar[512..768]
    float cr = 0.0f;                  // cell state (gate threads tid<128)
    const int gnl = tid >> 5;         // gate thread: nl (valid when tid<128)
    const int gb  = tid & 31;         // gate thread: b

    const float* wp = wT_lds + kg*WS + cg*4;
    const float* hp = h_lds  + kg*HS + bg*4;

    __syncthreads();

    for (int t = 0; t < TT; ++t) {
        const int parity = t & 1;
        const float4* hprev4 = (const float4*)(hT + (size_t)(d*2 + (parity ^ 1)) * 16384);
        float*        hnext  = hT + (size_t)(d*2 + parity) * 16384;

        // ---- prefetch xg (constant data; plain cached loads, stays in L2) ----
        float xgv[4] = {0.f, 0.f, 0.f, 0.f};
        if (tid < 128) {
            const float* xgs = xgp + (((size_t)d*TT + t)*65536) + (size_t)nblk*512;
            #pragma unroll
            for (int g = 0; g < 4; ++g)
                xgv[g] = xgs[(g*4 + gnl)*32 + gb];
        }

        // ---- stage hT -> LDS via sc loads, single drain (round-1 pattern;
        //      8 loads/thread at 512 threads) ----
        float4 hstg[8];
        #pragma unroll
        for (int i = 0; i < 8; ++i)
            hstg[i] = ld_b128_sc(hprev4 + i*512 + tid);
        asm volatile("s_waitcnt vmcnt(0)" ::: "memory");
        __builtin_amdgcn_sched_barrier(0);
        #pragma unroll
        for (int i = 0; i < 8; ++i) {
            const int idx = i*512 + tid;
            const int k  = idx >> 3;
            const int b4 = idx & 7;
            *(float4*)&h_lds[k*HS + b4*4] = hstg[i];
        }
        __syncthreads();

        // ---- MAC: acc[ci][bi], k = kk*16 + kg ----
        float acc[4][4];
        #pragma unroll
        for (int i = 0; i < 4; ++i)
            #pragma unroll
            for (int j = 0; j < 4; ++j) acc[i][j] = 0.0f;
        #pragma unroll 8
        for (int kk = 0; kk < 32; ++kk) {
            const float4 wv = *(const float4*)(wp + kk*(16*WS));
            const float4 hv = *(const float4*)(hp + kk*(16*HS));
            acc[0][0] += wv.x*hv.x; acc[0][1] += wv.x*hv.y; acc[0][2] += wv.x*hv.z; acc[0][3] += wv.x*hv.w;
            acc[1][0] += wv.y*hv.x; acc[1][1] += wv.y*hv.y; acc[1][2] += wv.y*hv.z; acc[1][3] += wv.y*hv.w;
            acc[2][0] += wv.z*hv.x; acc[2][1] += wv.z*hv.y; acc[2][2] += wv.z*hv.z; acc[2][3] += wv.z*hv.w;
            acc[3][0] += wv.w*hv.x; acc[3][1] += wv.w*hv.y; acc[3][2] += wv.w*hv.z; acc[3][3] += wv.w*hv.w;
        }

        // ---- reduce k-partials across kg (lane bits 0..3) ----
        #pragma unroll
        for (int i = 0; i < 4; ++i)
            #pragma unroll
            for (int j = 0; j < 4; ++j) {
                float v = acc[i][j];
                v += __shfl_xor(v, 1);
                v += __shfl_xor(v, 2);
                v += __shfl_xor(v, 4);
                v += __shfl_xor(v, 8);
                acc[i][j] = v;
            }
        if (kg < 4) {
            const int ci = kg;
            *(float4*)&gbuf[(cg*4 + ci)*32 + bg*4] =
                make_float4(acc[ci][0], acc[ci][1], acc[ci][2], acc[ci][3]);
        }
        __syncthreads();

        // ---- gate combine: 128 threads, one (nl, b) each ----
        if (tid < 128) {
            const int nl = gnl;
            const int b  = gb;
            const float gi = gbuf[(0*4 + nl)*32 + b] + xgv[0];
            const float gf = gbuf[(1*4 + nl)*32 + b] + xgv[1];
            const float gc = gbuf[(2*4 + nl)*32 + b] + xgv[2];
            const float go = gbuf[(3*4 + nl)*32 + b] + xgv[3];
            const float cn = sigm(gf)*cr + sigm(gi)*tanhf(gc);
            cr = cn;
            const float hv = sigm(go)*tanhf(cn);
            const int ng = nblk*4 + nl;
            st_b32_sc(hnext + (size_t)ng*32 + b, hv);             // write-through to L3
            const size_t oi = ((size_t)b*TT + t)*(2*HH) + (size_t)d*HH + ng;
            if constexpr (F32) ((float*)out)[oi] = hv;
            else               ((u16*)out)[oi]   = f2bf(hv);
        }
        grid_bar_dir(bard, wgl, 8 * (t + 1));
    }
}

__global__ __launch_bounds__(512, 1) void lstm_rec(
    const void* __restrict__ WhhF, const void* __restrict__ WhhB,
    const float* __restrict__ xgp, float* __restrict__ hT,
    int* __restrict__ bar, const int* __restrict__ flag,
    void* __restrict__ out)
{
    __shared__ float wT_lds[512 * WS];   // 40 KB
    __shared__ float h_lds[512 * HS];    // 72 KB
    __shared__ float gbuf[512];          //  2 KB
    const int wg   = blockIdx.x;
    const int d    = wg >> 7;
    const int nblk = wg & 127;
    const void* Whh = d ? WhhB : WhhF;
    if (*flag) rec_body<true >(Whh, xgp, hT, bar, out, d, nblk, wg & 127, wT_lds, h_lds, gbuf);
    else       rec_body<false>(Whh, xgp, hT, bar, out, d, nblk, wg & 127, wT_lds, h_lds, gbuf);
}

// ---------------- fallback: proven round-3/4 per-step kernel ----------------
template<bool F32>
__device__ __forceinline__ void step_body(
    const void* __restrict__ x,
    const void* __restrict__ Wih, const void* __restrict__ bih,
    const void* __restrict__ Whh, const void* __restrict__ bhh,
    const float* __restrict__ h_prev, float* __restrict__ h_next,
    float* __restrict__ c_st, void* __restrict__ out,
    int d, int nblk, int t, int t_src, float* __restrict__ gbuf)
{
    const int tid = threadIdx.x;
    const int c0  = tid & 15;
    const int g   = c0 >> 2;
    const int nl  = c0 & 3;
    const int bq  = tid >> 4;
    const int col = g*512 + nblk*4 + nl;
    const int b0 = bq*2, b1 = b0 + 1;

    float p00=0.f,p01=0.f,p02=0.f,p03=0.f;
    float p10=0.f,p11=0.f,p12=0.f,p13=0.f;
    {
        const size_t xo0 = ((size_t)b0*TT + t_src) * EE;
        const size_t xo1 = ((size_t)b1*TT + t_src) * EE;
        #pragma unroll 4
        for (int k = 0; k < EE; k += 4) {
            const size_t wi = (size_t)k*GG + col;
            float w0 = ldw<F32>(Wih, wi);
            float w1 = ldw<F32>(Wih, wi +   (size_t)GG);
            float w2 = ldw<F32>(Wih, wi + 2*(size_t)GG);
            float w3 = ldw<F32>(Wih, wi + 3*(size_t)GG);
            float4 a0 = ld4<F32>(x, xo0 + k);
            float4 a1 = ld4<F32>(x, xo1 + k);
            p00 += w0*a0.x; p01 += w1*a0.y; p02 += w2*a0.z; p03 += w3*a0.w;
            p10 += w0*a1.x; p11 += w1*a1.y; p12 += w2*a1.z; p13 += w3*a1.w;
        }
    }
    {
        const float* hr0 = h_prev + (size_t)b0*HH;
        const float* hr1 = h_prev + (size_t)b1*HH;
        #pragma unroll 4
        for (int k = 0; k < HH; k += 4) {
            const size_t wi = (size_t)k*GG + col;
            float w0 = ldw<F32>(Whh, wi);
            float w1 = ldw<F32>(Whh, wi +   (size_t)GG);
            float w2 = ldw<F32>(Whh, wi + 2*(size_t)GG);
            float w3 = ldw<F32>(Whh, wi + 3*(size_t)GG);
            float4 v0 = *(const float4*)(hr0 + k);
            float4 v1 = *(const float4*)(hr1 + k);
            p00 += w0*v0.x; p01 += w1*v0.y; p02 += w2*v0.z; p03 += w3*v0.w;
            p10 += w0*v1.x; p11 += w1*v1.y; p12 += w2*v1.z; p13 += w3*v1.w;
        }
    }
    const float bias = ldw<F32>(bih, col) + ldw<F32>(bhh, col);
    gbuf[tid*2 + 0] = p00 + p01 + p02 + p03 + bias;
    gbuf[tid*2 + 1] = p10 + p11 + p12 + p13 + bias;
    __syncthreads();
    if (c0 < 4) {
        const int nlc = c0;
        const int ng  = nblk*4 + nlc;
        #pragma unroll
        for (int bi = 0; bi < 2; ++bi) {
            const int b = bq*2 + bi;
            const float gi = gbuf[(bq*16 + 0  + nlc)*2 + bi];
            const float gf = gbuf[(bq*16 + 4  + nlc)*2 + bi];
            const float gc = gbuf[(bq*16 + 8  + nlc)*2 + bi];
            const float go = gbuf[(bq*16 + 12 + nlc)*2 + bi];
            const size_t ci = (size_t)b*HH + ng;
            const float cp = c_st[ci];
            const float cn = sigm(gf)*cp + sigm(gi)*tanhf(gc);
            c_st[ci] = cn;
            const float hv = sigm(go)*tanhf(cn);
            h_next[ci] = hv;
            const size_t oi = ((size_t)b*TT + t)*(2*HH) + (size_t)d*HH + ng;
            if constexpr (F32) ((float*)out)[oi] = hv;
            else               ((u16*)out)[oi]   = f2bf(hv);
        }
    }
}

__global__ __launch_bounds__(256) void lstm_step(
    const void* __restrict__ x,
    const void* __restrict__ WihF, const void* __restrict__ bihF,
    const void* __restrict__ WhhF, const void* __restrict__ bhhF,
    const void* __restrict__ WihB, const void* __restrict__ bihB,
    const void* __restrict__ WhhB, const void* __restrict__ bhhB,
    float* __restrict__ h_buf, float* __restrict__ c_buf,
    const int* __restrict__ flag, void* __restrict__ out, int t)
{
    __shared__ float gbuf[512];
    const int bid  = blockIdx.x;
    const int d    = bid >> 7;
    const int nblk = bid & 127;
    const void* Wih = d ? WihB : WihF;
    const void* Whh = d ? WhhB : WhhF;
    const void* bih = d ? bihB : bihF;
    const void* bhh = d ? bhhB : bhhF;
    const int t_src  = d ? (TT - 1 - t) : t;
    const int parity = t & 1;
    const float* h_prev = h_buf + ((size_t)(d*2 + (parity ^ 1))) * BB * HH;
    float*       h_next = h_buf + ((size_t)(d*2 + parity)) * BB * HH;
    float*       c_st   = c_buf + (size_t)d * BB * HH;
    if (*flag) step_body<true >(x, Wih, bih, Whh, bhh, h_prev, h_next, c_st, out, d, nblk, t, t_src, gbuf);
    else       step_body<false>(x, Wih, bih, Whh, bhh, h_prev, h_next, c_st, out, d, nblk, t, t_src, gbuf);
}

// ---------------- host ----------------
extern "C" void kernel_launch(void* const* d_in, const int* in_sizes, int n_in,
                              void* d_out, int out_size, void* d_ws, size_t ws_size,
                              hipStream_t stream) {
    const void* x    = d_in[0];
    const void* WihF = d_in[1];
    const void* bihF = d_in[2];
    const void* WhhF = d_in[3];
    const void* bhhF = d_in[4];
    const void* WihB = d_in[5];
    const void* bihB = d_in[6];
    const void* WhhB = d_in[7];
    const void* bhhB = d_in[8];

    float* ws = (float*)d_ws;

    // layout (floats): xg[33554432] | h[65536] | c[32768] | bar[1024 ints] | flag
    const size_t off_xg = 0;
    const size_t off_h  = (size_t)2*TT*BB*GG;            // 33554432
    const size_t off_c  = off_h + (size_t)2*2*BB*HH;     // + 65536
    const size_t off_b  = off_c + (size_t)2*BB*HH;       // + 32768
    const size_t off_f  = off_b + 1024;
    const size_t need_bytes = (off_f + 16) * sizeof(float);

    if (ws_size >= need_bytes) {
        float* xgp  = ws + off_xg;
        float* hT   = ws + off_h;     // transposed: [2][2][512 k][32 b]
        float* cbuf = ws + off_c;     // unused by fast path (zeroed anyway)
        int*   bar  = (int*)(ws + off_b);
        int*   flag = (int*)(ws + off_f);

        init_state<<<64, 256, 0, stream>>>((const u16*)bihF, hT, cbuf, bar, flag);
        xg_gemm<<<8192, 256, 0, stream>>>(x, WihF, bihF, bhhF, WihB, bihB, bhhB, xgp, flag);
        lstm_rec<<<256, 512, 0, stream>>>(WhhF, WhhB, xgp, hT, bar, flag, d_out);
    } else {
        float* h_buf = ws;
        float* c_buf = ws + (size_t)2*2*BB*HH;
        int*   bar   = (int*)(c_buf + (size_t)2*BB*HH);
        int*   flag  = (int*)(bar + 1024);
        init_state<<<64, 256, 0, stream>>>((const u16*)bihF, h_buf, c_buf, bar, flag);
        for (int t = 0; t < TT; ++t) {
            lstm_step<<<256, 256, 0, stream>>>(x, WihF, bihF, WhhF, bhhF,
                                               WihB, bihB, WhhB, bhhB,
                                               h_buf, c_buf, flag, d_out, t);
        }
    }
}

// Round 8
// 2262.490 us; speedup vs baseline: 2.1711x; 1.2111x over previous
//
#include <hip/hip_runtime.h>
#include <hip/hip_bf16.h>
#include <math.h>

static constexpr int BB = 32;
static constexpr int TT = 256;
static constexpr int EE = 512;
static constexpr int HH = 512;
static constexpr int GG = 2048;  // 4H

static constexpr int HS2 = 12;   // h_lds row stride: 8 data + 4 pad (sigma=3, odd)

using u16 = unsigned short;

__device__ __forceinline__ float bf2f(u16 u) {
    return __uint_as_float(((unsigned int)u) << 16);
}
__device__ __forceinline__ u16 f2bf(float f) {
    unsigned int u = __float_as_uint(f);
    unsigned int r = 0x7FFFu + ((u >> 16) & 1u);
    return (u16)((u + r) >> 16);
}
__device__ __forceinline__ float sigm(float x) {
    return 1.0f / (1.0f + expf(-x));
}

// ---- coherence-point (L3) accessors: sc0 sc1 = system-scope, bypass L1/L2.
// All cross-WG mutable data goes through these -> NO wbl2/inv ever needed in
// the recurrent loop -> read-only xg/Whh stay L2-cached across all 256 steps.
__device__ __forceinline__ float4 ld_b128_sc(const float4* p) {
    float4 v;
    asm volatile("global_load_dwordx4 %0, %1, off sc0 sc1" : "=v"(v) : "v"(p));
    return v;
}
__device__ __forceinline__ void st_b32_sc(float* p, float v) {
    asm volatile("global_store_dword %0, %1, off sc0 sc1" :: "v"(p), "v"(v) : "memory");
}

template<bool F32>
__device__ __forceinline__ float ldw(const void* p, size_t i) {
    if constexpr (F32) return ((const float*)p)[i];
    else               return bf2f(((const u16*)p)[i]);
}
template<bool F32>
__device__ __forceinline__ float4 ld4(const void* p, size_t i) {  // i % 4 == 0
    if constexpr (F32) {
        return *(const float4*)((const float*)p + i);
    } else {
        ushort4 v = *(const ushort4*)((const u16*)p + i);
        return make_float4(bf2f(v.x), bf2f(v.y), bf2f(v.z), bf2f(v.w));
    }
}

// ---------------- init: zero state, zero barrier, detect dtype ----------------
__global__ void init_state(const u16* __restrict__ bih_probe,
                           float* __restrict__ h_st, float* __restrict__ c_st,
                           int* __restrict__ bar, int* __restrict__ flag) {
    size_t i = (size_t)blockIdx.x * blockDim.x + threadIdx.x;
    size_t stride = (size_t)gridDim.x * blockDim.x;
    for (size_t j = i; j < (size_t)2*2*BB*HH; j += stride) h_st[j] = 0.0f;
    for (size_t j = i; j < (size_t)2*BB*HH;   j += stride) c_st[j] = 0.0f;
    for (size_t j = i; j < 1024;              j += stride) bar[j] = 0;
    if (blockIdx.x == 0 && threadIdx.x == 0) {
        int f = 0;
        for (int k = 0; k < 2048; ++k) {
            int e = (bih_probe[k] >> 7) & 0xFF;
            if (e >= 127) f = 1;
        }
        *flag = f;
    }
}

// ---------------- phase 1: xg = x @ Wih + bih + bhh ----------------
// Output layout (round 8, per (d,t)): [bg8(4)][wgc(32)][hcl(16)][g(4)][b(8)]
// where col = g*512 + wgc*16 + hcl, b = bg8*8 + brem. Per rec-WG per-step
// slice = contiguous 2 KB at bg8*16384 + wgc*512.
template<bool F32>
__device__ __forceinline__ void xg_body(
    const void* __restrict__ x, const void* __restrict__ Wih,
    const void* __restrict__ bih, const void* __restrict__ bhh,
    float* __restrict__ xgp, int d, int mt, int nt, float* b_lds)
{
    const int tid = threadIdx.x;
    const int tn = tid & 15;
    const int tm = tid >> 4;
    const int m0 = mt * 64;
    const int n0 = nt * 64;

    size_t a_off[4];
    #pragma unroll
    for (int i = 0; i < 4; ++i) {
        const int m = m0 + 4*tm + i;
        const int t = m >> 5, b = m & 31;
        const int t_src = d ? (TT - 1 - t) : t;
        a_off[i] = ((size_t)b * TT + t_src) * EE;
    }

    float acc[4][4];
    #pragma unroll
    for (int i = 0; i < 4; ++i)
        #pragma unroll
        for (int j = 0; j < 4; ++j) acc[i][j] = 0.0f;

    const int kr = tid >> 2;
    const int nc = (tid & 3) * 16;

    for (int k0 = 0; k0 < EE; k0 += 64) {
        __syncthreads();
        #pragma unroll 4
        for (int e = 0; e < 16; ++e)
            b_lds[kr*64 + nc + e] = ldw<F32>(Wih, (size_t)(k0 + kr)*GG + n0 + nc + e);
        __syncthreads();

        #pragma unroll 2
        for (int kk = 0; kk < 64; kk += 4) {
            float4 av[4];
            #pragma unroll
            for (int i = 0; i < 4; ++i) av[i] = ld4<F32>(x, a_off[i] + k0 + kk);
            #pragma unroll
            for (int j = 0; j < 4; ++j) {
                const float4 bv = *(const float4*)&b_lds[(kk + j)*64 + 4*tn];
                #pragma unroll
                for (int i = 0; i < 4; ++i) {
                    const float a = (j == 0) ? av[i].x : (j == 1) ? av[i].y
                                  : (j == 2) ? av[i].z : av[i].w;
                    acc[i][0] += a * bv.x; acc[i][1] += a * bv.y;
                    acc[i][2] += a * bv.z; acc[i][3] += a * bv.w;
                }
            }
        }
    }

    const int mbase = m0 + 4*tm;
    const int tt = mbase >> 5, bb = mbase & 31;   // 4 rows share t; b quad-aligned
    #pragma unroll
    for (int j = 0; j < 4; ++j) {
        const int col  = n0 + 4*tn + j;
        const float bs = ldw<F32>(bih, col) + ldw<F32>(bhh, col);
        const int g    = col >> 9;
        const int hc   = col & 511;
        const int wgc  = hc >> 4;
        const int hcl  = hc & 15;
        const int bg8  = bb >> 3;
        const int brem = bb & 7;      // quad-aligned -> 0 or 4
        const size_t idx = (((size_t)d*TT + tt)*65536)
                         + (size_t)bg8*16384 + (size_t)wgc*512
                         + (size_t)(hcl*4 + g)*8 + brem;
        float4 v = make_float4(acc[0][j] + bs, acc[1][j] + bs,
                               acc[2][j] + bs, acc[3][j] + bs);
        *(float4*)&xgp[idx] = v;
    }
}

__global__ __launch_bounds__(256) void xg_gemm(
    const void* __restrict__ x,
    const void* __restrict__ WihF, const void* __restrict__ bihF, const void* __restrict__ bhhF,
    const void* __restrict__ WihB, const void* __restrict__ bihB, const void* __restrict__ bhhB,
    float* __restrict__ xgp, const int* __restrict__ flag)
{
    __shared__ float b_lds[64 * 64];
    const int bid = blockIdx.x;
    const int d  = bid >> 12;
    const int r  = bid & 4095;
    const int mt = r >> 5;
    const int nt = r & 31;
    const void* Wih = d ? WihB : WihF;
    const void* bih = d ? bihB : bihF;
    const void* bhh = d ? bhhB : bhhF;
    if (*flag) xg_body<true >(x, Wih, bih, bhh, xgp, d, mt, nt, b_lds);
    else       xg_body<false>(x, Wih, bih, bhh, xgp, d, mt, nt, b_lds);
}

// ---------------- phase 2: persistent recurrent kernel (round 8) ----------------
// 8 INDEPENDENT CHAINS: chain = (dir, batch-octet). 32 WGs per chain; each WG
// owns 16 h-cols x 4 gates (64 gate-cols, 128 KB weights in LDS, XOR-swizzled
// byte ^= (k&7)<<4 -> conflict-free b128 reads, no padding) for 8 batches.
// Per-WG MAC work identical to R1 (262k MAC, acc[4][4] inner loop). Changes:
//   - sync group 128 -> 32 WGs, single-level relaxed agent counter per chain
//     (skew worst-of-32; 8 chains drift independently)
//   - h exchange per WG 64 KB -> 16 KB (chain h = [512 k][8 b] fp32)
// Protocol mechanics R1-verbatim: sc0/sc1 h write-through + bulk sc loads,
// vmcnt(0) + WG barrier before arrival add, tid0 poll + s_sleep.
// Thread map: kg = tid&7 (k-split, lane bits 0..2), bq = (tid>>3)&1 (batch
// quad), cq = tid>>4 (col quad: LDS cols cq*4..+3, col c = hcl*4+g).
// Bank checks: wv quad = (cq^kg)&7 distinct across kg; hv quad = (3k+bq)&7
// distinct (HS2=12, sigma 3).
template<bool F32>
__device__ __forceinline__ void rec_body(
    const void* __restrict__ Whh,
    const float* __restrict__ xgp,   // [2][256][4][32][16][4][8] fp32 (biases folded)
    float* __restrict__ hT,          // [8 chain][2 parity][512 k][8 b] fp32
    int* __restrict__ bar,
    void* __restrict__ out, int d, int bg8, int wgc,
    float* __restrict__ w_lds,       // [512][64] XOR-swizzled, 128 KB
    float* __restrict__ h_lds,       // [512][HS2]
    float* __restrict__ gbuf)        // [512] = [hcl][g][b]
{
    const int tid = threadIdx.x;
    const int kg = tid & 7;           // k-split (lane bits 0..2)
    const int bq = (tid >> 3) & 1;    // batch quad (0: b0-3, 1: b4-7)
    const int cq = tid >> 4;          // col quad (0..15): LDS cols cq*4..+3

    // ---- stage Whh once, XOR-swizzled: col c = hcl*4+g <-> gatecol =
    //      g*512 + wgc*16 + hcl. byte(k,c) = (k*256 + c*4) ^ ((k&7)<<4) ----
    {
        const int c  = tid & 63;
        const int kq = tid >> 6;
        const int gcol = (c & 3)*512 + wgc*16 + (c >> 2);
        char* wb = (char*)w_lds;
        for (int k = kq*128; k < kq*128 + 128; ++k) {
            const unsigned byte = (unsigned)(k*256 + c*4) ^ ((unsigned)(k & 7) << 4);
            *(float*)(wb + byte) = ldw<F32>(Whh, (size_t)k*GG + gcol);
        }
    }

    const int ch = d*4 + bg8;
    int* barc = bar + ch*128;         // one counter per chain, 512 B apart
    float* hTc = hT + (size_t)ch * 8192;   // [2][512][8]

    float cr = 0.0f;                  // cell state (gate threads tid<128)
    const int ghcl = tid >> 3;        // gate thread: local h-col (valid tid<128)
    const int gb   = tid & 7;         // gate thread: batch (octet-local)

    // MAC read bases
    const char* wpB = (const char*)w_lds + kg*256 + ((unsigned)(cq*16) ^ ((unsigned)kg << 4));
    const float* hp = h_lds + kg*HS2 + bq*4;

    __syncthreads();

    for (int t = 0; t < TT; ++t) {
        const int parity = t & 1;
        const float4* hprev4 = (const float4*)(hTc + (parity ^ 1) * 4096);
        float*        hnext  = hTc + parity * 4096;

        // ---- prefetch xg (read-only; plain cached loads, stays in L2) ----
        float xgv[4] = {0.f, 0.f, 0.f, 0.f};
        if (tid < 128) {
            const float* xgs = xgp + (((size_t)d*TT + t)*65536)
                             + (size_t)bg8*16384 + (size_t)wgc*512;
            #pragma unroll
            for (int g = 0; g < 4; ++g)
                xgv[g] = xgs[(ghcl*4 + g)*8 + gb];
        }

        // ---- stage chain h -> LDS via sc loads, single drain (16 KB) ----
        float4 hstg[4];
        #pragma unroll
        for (int i = 0; i < 4; ++i)
            hstg[i] = ld_b128_sc(hprev4 + i*256 + tid);
        asm volatile("s_waitcnt vmcnt(0)" ::: "memory");
        __builtin_amdgcn_sched_barrier(0);
        #pragma unroll
        for (int i = 0; i < 4; ++i) {
            const int idx = i*256 + tid;
            const int k  = idx >> 1;
            const int b4 = idx & 1;
            *(float4*)&h_lds[k*HS2 + b4*4] = hstg[i];
        }
        __syncthreads();

        // ---- MAC: acc[ci][bi] over k = kk*8 + kg ----
        float acc[4][4];
        #pragma unroll
        for (int i = 0; i < 4; ++i)
            #pragma unroll
            for (int j = 0; j < 4; ++j) acc[i][j] = 0.0f;
        #pragma unroll 8
        for (int kk = 0; kk < 64; ++kk) {
            const float4 wv = *(const float4*)(wpB + kk*2048);
            const float4 hv = *(const float4*)(hp + kk*(8*HS2));
            acc[0][0] += wv.x*hv.x; acc[0][1] += wv.x*hv.y; acc[0][2] += wv.x*hv.z; acc[0][3] += wv.x*hv.w;
            acc[1][0] += wv.y*hv.x; acc[1][1] += wv.y*hv.y; acc[1][2] += wv.y*hv.z; acc[1][3] += wv.y*hv.w;
            acc[2][0] += wv.z*hv.x; acc[2][1] += wv.z*hv.y; acc[2][2] += wv.z*hv.z; acc[2][3] += wv.z*hv.w;
            acc[3][0] += wv.w*hv.x; acc[3][1] += wv.w*hv.y; acc[3][2] += wv.w*hv.z; acc[3][3] += wv.w*hv.w;
        }

        // ---- reduce k-partials across kg (lane bits 0..2) ----
        #pragma unroll
        for (int i = 0; i < 4; ++i)
            #pragma unroll
            for (int j = 0; j < 4; ++j) {
                float v = acc[i][j];
                v += __shfl_xor(v, 1);
                v += __shfl_xor(v, 2);
                v += __shfl_xor(v, 4);
                acc[i][j] = v;
            }
        if (kg < 4) {
            const int ci = kg;
            *(float4*)&gbuf[(cq*4 + ci)*8 + bq*4] =
                make_float4(acc[ci][0], acc[ci][1], acc[ci][2], acc[ci][3]);
        }
        __syncthreads();

        // ---- gate combine: 128 threads, one (hcl, b) each ----
        if (tid < 128) {
            const float gi = gbuf[(ghcl*4 + 0)*8 + gb] + xgv[0];
            const float gf = gbuf[(ghcl*4 + 1)*8 + gb] + xgv[1];
            const float gc = gbuf[(ghcl*4 + 2)*8 + gb] + xgv[2];
            const float go = gbuf[(ghcl*4 + 3)*8 + gb] + xgv[3];
            const float cn = sigm(gf)*cr + sigm(gi)*tanhf(gc);
            cr = cn;
            const float hv = sigm(go)*tanhf(cn);
            const int hc = wgc*16 + ghcl;               // global h-col
            st_b32_sc(hnext + (size_t)hc*8 + gb, hv);   // write-through to L3
            const int bglob = bg8*8 + gb;
            const size_t oi = ((size_t)bglob*TT + t)*(2*HH) + (size_t)d*HH + hc;
            if constexpr (F32) ((float*)out)[oi] = hv;
            else               ((u16*)out)[oi]   = f2bf(hv);
        }

        // ---- chain barrier: drain, WG barrier, single-level relaxed add ----
        asm volatile("s_waitcnt vmcnt(0)" ::: "memory");
        __syncthreads();
        if (tid == 0) {
            __hip_atomic_fetch_add(barc, 1, __ATOMIC_RELAXED, __HIP_MEMORY_SCOPE_AGENT);
            const int tgt = 32 * (t + 1);
            while (__hip_atomic_load(barc, __ATOMIC_RELAXED, __HIP_MEMORY_SCOPE_AGENT) < tgt)
                __builtin_amdgcn_s_sleep(1);
        }
        __syncthreads();
    }
}

__global__ __launch_bounds__(256, 1) void lstm_rec(
    const void* __restrict__ WhhF, const void* __restrict__ WhhB,
    const float* __restrict__ xgp, float* __restrict__ hT,
    int* __restrict__ bar, const int* __restrict__ flag,
    void* __restrict__ out)
{
    __shared__ float w_lds[512 * 64];    // 128 KB (XOR-swizzled)
    __shared__ float h_lds[512 * HS2];   //  24 KB
    __shared__ float gbuf[512];          //   2 KB
    const int wg  = blockIdx.x;
    const int d   = wg >> 7;
    const int r   = wg & 127;
    const int bg8 = r >> 5;
    const int wgc = r & 31;
    const void* Whh = d ? WhhB : WhhF;
    if (*flag) rec_body<true >(Whh, xgp, hT, bar, out, d, bg8, wgc, w_lds, h_lds, gbuf);
    else       rec_body<false>(Whh, xgp, hT, bar, out, d, bg8, wgc, w_lds, h_lds, gbuf);
}

// ---------------- fallback: proven round-3/4 per-step kernel ----------------
template<bool F32>
__device__ __forceinline__ void step_body(
    const void* __restrict__ x,
    const void* __restrict__ Wih, const void* __restrict__ bih,
    const void* __restrict__ Whh, const void* __restrict__ bhh,
    const float* __restrict__ h_prev, float* __restrict__ h_next,
    float* __restrict__ c_st, void* __restrict__ out,
    int d, int nblk, int t, int t_src, float* __restrict__ gbuf)
{
    const int tid = threadIdx.x;
    const int c0  = tid & 15;
    const int g   = c0 >> 2;
    const int nl  = c0 & 3;
    const int bq  = tid >> 4;
    const int col = g*512 + nblk*4 + nl;
    const int b0 = bq*2, b1 = b0 + 1;

    float p00=0.f,p01=0.f,p02=0.f,p03=0.f;
    float p10=0.f,p11=0.f,p12=0.f,p13=0.f;
    {
        const size_t xo0 = ((size_t)b0*TT + t_src) * EE;
        const size_t xo1 = ((size_t)b1*TT + t_src) * EE;
        #pragma unroll 4
        for (int k = 0; k < EE; k += 4) {
            const size_t wi = (size_t)k*GG + col;
            float w0 = ldw<F32>(Wih, wi);
            float w1 = ldw<F32>(Wih, wi +   (size_t)GG);
            float w2 = ldw<F32>(Wih, wi + 2*(size_t)GG);
            float w3 = ldw<F32>(Wih, wi + 3*(size_t)GG);
            float4 a0 = ld4<F32>(x, xo0 + k);
            float4 a1 = ld4<F32>(x, xo1 + k);
            p00 += w0*a0.x; p01 += w1*a0.y; p02 += w2*a0.z; p03 += w3*a0.w;
            p10 += w0*a1.x; p11 += w1*a1.y; p12 += w2*a1.z; p13 += w3*a1.w;
        }
    }
    {
        const float* hr0 = h_prev + (size_t)b0*HH;
        const float* hr1 = h_prev + (size_t)b1*HH;
        #pragma unroll 4
        for (int k = 0; k < HH; k += 4) {
            const size_t wi = (size_t)k*GG + col;
            float w0 = ldw<F32>(Whh, wi);
            float w1 = ldw<F32>(Whh, wi +   (size_t)GG);
            float w2 = ldw<F32>(Whh, wi + 2*(size_t)GG);
            float w3 = ldw<F32>(Whh, wi + 3*(size_t)GG);
            float4 v0 = *(const float4*)(hr0 + k);
            float4 v1 = *(const float4*)(hr1 + k);
            p00 += w0*v0.x; p01 += w1*v0.y; p02 += w2*v0.z; p03 += w3*v0.w;
            p10 += w0*v1.x; p11 += w1*v1.y; p12 += w2*v1.z; p13 += w3*v1.w;
        }
    }
    const float bias = ldw<F32>(bih, col) + ldw<F32>(bhh, col);
    gbuf[tid*2 + 0] = p00 + p01 + p02 + p03 + bias;
    gbuf[tid*2 + 1] = p10 + p11 + p12 + p13 + bias;
    __syncthreads();
    if (c0 < 4) {
        const int nlc = c0;
        const int ng  = nblk*4 + nlc;
        #pragma unroll
        for (int bi = 0; bi < 2; ++bi) {
            const int b = bq*2 + bi;
            const float gi = gbuf[(bq*16 + 0  + nlc)*2 + bi];
            const float gf = gbuf[(bq*16 + 4  + nlc)*2 + bi];
            const float gc = gbuf[(bq*16 + 8  + nlc)*2 + bi];
            const float go = gbuf[(bq*16 + 12 + nlc)*2 + bi];
            const size_t ci = (size_t)b*HH + ng;
            const float cp = c_st[ci];
            const float cn = sigm(gf)*cp + sigm(gi)*tanhf(gc);
            c_st[ci] = cn;
            const float hv = sigm(go)*tanhf(cn);
            h_next[ci] = hv;
            const size_t oi = ((size_t)b*TT + t)*(2*HH) + (size_t)d*HH + ng;
            if constexpr (F32) ((float*)out)[oi] = hv;
            else               ((u16*)out)[oi]   = f2bf(hv);
        }
    }
}

__global__ __launch_bounds__(256) void lstm_step(
    const void* __restrict__ x,
    const void* __restrict__ WihF, const void* __restrict__ bihF,
    const void* __restrict__ WhhF, const void* __restrict__ bhhF,
    const void* __restrict__ WihB, const void* __restrict__ bihB,
    const void* __restrict__ WhhB, const void* __restrict__ bhhB,
    float* __restrict__ h_buf, float* __restrict__ c_buf,
    const int* __restrict__ flag, void* __restrict__ out, int t)
{
    __shared__ float gbuf[512];
    const int bid  = blockIdx.x;
    const int d    = bid >> 7;
    const int nblk = bid & 127;
    const void* Wih = d ? WihB : WihF;
    const void* Whh = d ? WhhB : WhhF;
    const void* bih = d ? bihB : bihF;
    const void* bhh = d ? bhhB : bhhF;
    const int t_src  = d ? (TT - 1 - t) : t;
    const int parity = t & 1;
    const float* h_prev = h_buf + ((size_t)(d*2 + (parity ^ 1))) * BB * HH;
    float*       h_next = h_buf + ((size_t)(d*2 + parity)) * BB * HH;
    float*       c_st   = c_buf + (size_t)d * BB * HH;
    if (*flag) step_body<true >(x, Wih, bih, Whh, bhh, h_prev, h_next, c_st, out, d, nblk, t, t_src, gbuf);
    else       step_body<false>(x, Wih, bih, Whh, bhh, h_prev, h_next, c_st, out, d, nblk, t, t_src, gbuf);
}

// ---------------- host ----------------
extern "C" void kernel_launch(void* const* d_in, const int* in_sizes, int n_in,
                              void* d_out, int out_size, void* d_ws, size_t ws_size,
                              hipStream_t stream) {
    const void* x    = d_in[0];
    const void* WihF = d_in[1];
    const void* bihF = d_in[2];
    const void* WhhF = d_in[3];
    const void* bhhF = d_in[4];
    const void* WihB = d_in[5];
    const void* bihB = d_in[6];
    const void* WhhB = d_in[7];
    const void* bhhB = d_in[8];

    float* ws = (float*)d_ws;

    // layout (floats): xg[33554432] | h[65536] | c[32768] | bar[1024 ints] | flag
    const size_t off_xg = 0;
    const size_t off_h  = (size_t)2*TT*BB*GG;            // 33554432
    const size_t off_c  = off_h + (size_t)2*2*BB*HH;     // + 65536
    const size_t off_b  = off_c + (size_t)2*BB*HH;       // + 32768
    const size_t off_f  = off_b + 1024;
    const size_t need_bytes = (off_f + 16) * sizeof(float);

    if (ws_size >= need_bytes) {
        float* xgp  = ws + off_xg;
        float* hT   = ws + off_h;     // [8 chain][2 parity][512 k][8 b]
        float* cbuf = ws + off_c;     // unused by fast path (zeroed anyway)
        int*   bar  = (int*)(ws + off_b);
        int*   flag = (int*)(ws + off_f);

        init_state<<<64, 256, 0, stream>>>((const u16*)bihF, hT, cbuf, bar, flag);
        xg_gemm<<<8192, 256, 0, stream>>>(x, WihF, bihF, bhhF, WihB, bihB, bhhB, xgp, flag);
        lstm_rec<<<256, 256, 0, stream>>>(WhhF, WhhB, xgp, hT, bar, flag, d_out);
    } else {
        float* h_buf = ws;
        float* c_buf = ws + (size_t)2*2*BB*HH;
        int*   bar   = (int*)(c_buf + (size_t)2*BB*HH);
        int*   flag  = (int*)(bar + 1024);
        init_state<<<64, 256, 0, stream>>>((const u16*)bihF, h_buf, c_buf, bar, flag);
        for (int t = 0; t < TT; ++t) {
            lstm_step<<<256, 256, 0, stream>>>(x, WihF, bihF, WhhF, bhhF,
                                               WihB, bihB, WhhB, bhhB,
                                               h_buf, c_buf, flag, d_out, t);
        }
    }
}

// Round 10
// 2200.216 us; speedup vs baseline: 2.2325x; 1.0283x over previous
//
#include <hip/hip_runtime.h>
#include <hip/hip_bf16.h>
#include <math.h>

static constexpr int BB = 32;
static constexpr int TT = 256;
static constexpr int EE = 512;
static constexpr int HH = 512;
static constexpr int GG = 2048;  // 4H

static constexpr int HS2 = 12;   // h_lds row stride: 8 data + 4 pad (sigma=3, odd)

using u16 = unsigned short;
typedef float f32x4 __attribute__((ext_vector_type(4)));

__device__ __forceinline__ float bf2f(u16 u) {
    return __uint_as_float(((unsigned int)u) << 16);
}
__device__ __forceinline__ u16 f2bf(float f) {
    unsigned int u = __float_as_uint(f);
    unsigned int r = 0x7FFFu + ((u >> 16) & 1u);
    return (u16)((u + r) >> 16);
}
__device__ __forceinline__ float sigm(float x) {
    return 1.0f / (1.0f + expf(-x));
}

// ---- coherence-point (L3) accessors: sc0 sc1 = system-scope, bypass L1/L2.
// All cross-WG mutable data goes through these -> NO wbl2/inv ever needed in
// the recurrent loop -> read-only Whh stays L2-cached across all 256 steps.
__device__ __forceinline__ float4 ld_b128_sc(const float4* p) {
    f32x4 v;
    asm volatile("global_load_dwordx4 %0, %1, off sc0 sc1" : "=v"(v) : "v"(p));
    return make_float4(v.x, v.y, v.z, v.w);
}
__device__ __forceinline__ void st_b32_sc(float* p, float v) {
    asm volatile("global_store_dword %0, %1, off sc0 sc1" :: "v"(p), "v"(v) : "memory");
}
__device__ __forceinline__ void st_b128_sc(float* p, float4 v) {
    f32x4 vv = {v.x, v.y, v.z, v.w};   // native vector type: valid "v" input
    asm volatile("global_store_dwordx4 %0, %1, off sc0 sc1" :: "v"(p), "v"(vv) : "memory");
}

template<bool F32>
__device__ __forceinline__ float ldw(const void* p, size_t i) {
    if constexpr (F32) return ((const float*)p)[i];
    else               return bf2f(((const u16*)p)[i]);
}
template<bool F32>
__device__ __forceinline__ float4 ld4(const void* p, size_t i) {  // i % 4 == 0
    if constexpr (F32) {
        return *(const float4*)((const float*)p + i);
    } else {
        ushort4 v = *(const ushort4*)((const u16*)p + i);
        return make_float4(bf2f(v.x), bf2f(v.y), bf2f(v.z), bf2f(v.w));
    }
}

// ---------------- init: zero state, zero barriers/ready, detect dtype ----------------
// bar region (2048 ints): [ch*128] chain counters (ch 0..7), [1536..1791] xg
// ready counters (2 dirs x 128 mt).
__global__ void init_state(const u16* __restrict__ bih_probe,
                           float* __restrict__ h_st, float* __restrict__ c_st,
                           int* __restrict__ bar, int* __restrict__ flag) {
    size_t i = (size_t)blockIdx.x * blockDim.x + threadIdx.x;
    size_t stride = (size_t)gridDim.x * blockDim.x;
    for (size_t j = i; j < (size_t)2*2*BB*HH; j += stride) h_st[j] = 0.0f;
    for (size_t j = i; j < (size_t)2*BB*HH;   j += stride) c_st[j] = 0.0f;
    for (size_t j = i; j < 2048;              j += stride) bar[j] = 0;
    if (blockIdx.x == 0 && threadIdx.x == 0) {
        int f = 0;
        for (int k = 0; k < 2048; ++k) {
            int e = (bih_probe[k] >> 7) & 0xFF;
            if (e >= 127) f = 1;
        }
        *flag = f;
    }
}

// ---------------- phase 1: xg = x @ Wih + bih + bhh ----------------
// Output layout (per (d,t)): [bg8(4)][wgc(32)][hcl(16)][g(4)][b(8)]
// where col = g*512 + wgc*16 + hcl, b = bg8*8 + brem. Per rec-WG per-step
// slice = contiguous 2 KB at bg8*16384 + wgc*512.
// Round 9: xg stores are sc0 sc1 (write-through to L3) so the concurrently
// running lstm_rec observes them; per-(d,mt) completion counter signals
// readiness of steps t = 2mt, 2mt+1.
template<bool F32>
__device__ __forceinline__ void xg_body(
    const void* __restrict__ x, const void* __restrict__ Wih,
    const void* __restrict__ bih, const void* __restrict__ bhh,
    float* __restrict__ xgp, int d, int mt, int nt, float* b_lds)
{
    const int tid = threadIdx.x;
    const int tn = tid & 15;
    const int tm = tid >> 4;
    const int m0 = mt * 64;
    const int n0 = nt * 64;

    size_t a_off[4];
    #pragma unroll
    for (int i = 0; i < 4; ++i) {
        const int m = m0 + 4*tm + i;
        const int t = m >> 5, b = m & 31;
        const int t_src = d ? (TT - 1 - t) : t;
        a_off[i] = ((size_t)b * TT + t_src) * EE;
    }

    float acc[4][4];
    #pragma unroll
    for (int i = 0; i < 4; ++i)
        #pragma unroll
        for (int j = 0; j < 4; ++j) acc[i][j] = 0.0f;

    const int kr = tid >> 2;
    const int nc = (tid & 3) * 16;

    for (int k0 = 0; k0 < EE; k0 += 64) {
        __syncthreads();
        #pragma unroll 4
        for (int e = 0; e < 16; ++e)
            b_lds[kr*64 + nc + e] = ldw<F32>(Wih, (size_t)(k0 + kr)*GG + n0 + nc + e);
        __syncthreads();

        #pragma unroll 2
        for (int kk = 0; kk < 64; kk += 4) {
            float4 av[4];
            #pragma unroll
            for (int i = 0; i < 4; ++i) av[i] = ld4<F32>(x, a_off[i] + k0 + kk);
            #pragma unroll
            for (int j = 0; j < 4; ++j) {
                const float4 bv = *(const float4*)&b_lds[(kk + j)*64 + 4*tn];
                #pragma unroll
                for (int i = 0; i < 4; ++i) {
                    const float a = (j == 0) ? av[i].x : (j == 1) ? av[i].y
                                  : (j == 2) ? av[i].z : av[i].w;
                    acc[i][0] += a * bv.x; acc[i][1] += a * bv.y;
                    acc[i][2] += a * bv.z; acc[i][3] += a * bv.w;
                }
            }
        }
    }

    const int mbase = m0 + 4*tm;
    const int tt = mbase >> 5, bb = mbase & 31;   // 4 rows share t; b quad-aligned
    #pragma unroll
    for (int j = 0; j < 4; ++j) {
        const int col  = n0 + 4*tn + j;
        const float bs = ldw<F32>(bih, col) + ldw<F32>(bhh, col);
        const int g    = col >> 9;
        const int hc   = col & 511;
        const int wgc  = hc >> 4;
        const int hcl  = hc & 15;
        const int bg8  = bb >> 3;
        const int brem = bb & 7;      // quad-aligned -> 0 or 4
        const size_t idx = (((size_t)d*TT + tt)*65536)
                         + (size_t)bg8*16384 + (size_t)wgc*512
                         + (size_t)(hcl*4 + g)*8 + brem;
        float4 v = make_float4(acc[0][j] + bs, acc[1][j] + bs,
                               acc[2][j] + bs, acc[3][j] + bs);
        st_b128_sc(&xgp[idx], v);     // write-through to L3 (visible to rec)
    }
}

__global__ __launch_bounds__(256) void xg_gemm(
    const void* __restrict__ x,
    const void* __restrict__ WihF, const void* __restrict__ bihF, const void* __restrict__ bhhF,
    const void* __restrict__ WihB, const void* __restrict__ bihB, const void* __restrict__ bhhB,
    float* __restrict__ xgp, const int* __restrict__ flag,
    int* __restrict__ xgr)
{
    __shared__ float b_lds[64 * 64];
    // mt-major bid order: tiles complete in scan-time order for both dirs,
    // so the overlapped lstm_rec unblocks t=0,1,2,... promptly.
    const int bid = blockIdx.x;
    const int mt = bid >> 6;          // 0..127 (t = 2mt, 2mt+1)
    const int d  = (bid >> 5) & 1;
    const int nt = bid & 31;
    const void* Wih = d ? WihB : WihF;
    const void* bih = d ? bihB : bihF;
    const void* bhh = d ? bhhB : bhhF;
    if (*flag) xg_body<true >(x, Wih, bih, bhh, xgp, d, mt, nt, b_lds);
    else       xg_body<false>(x, Wih, bih, bhh, xgp, d, mt, nt, b_lds);
    // completion: all stores acked at L3, then one relaxed agent RMW
    asm volatile("s_waitcnt vmcnt(0)" ::: "memory");
    __syncthreads();
    if (threadIdx.x == 0)
        __hip_atomic_fetch_add(&xgr[d*128 + mt], 1,
                               __ATOMIC_RELAXED, __HIP_MEMORY_SCOPE_AGENT);
}

// ---------------- phase 2: persistent recurrent kernel (round 8 + overlap) ----------------
// 8 INDEPENDENT CHAINS: chain = (dir, batch-octet). 32 WGs per chain; each WG
// owns 16 h-cols x 4 gates (64 gate-cols, 128 KB weights in LDS, XOR-swizzled
// byte ^= (k&7)<<4) for 8 batches. Launched right after xg_gemm: HSA
// dispatches all xg WGs first (they never block -> no deadlock); rec WGs
// trickle in as CUs free; chains come online in bid order. tid0 polls the
// per-(d,mt) ready counter once per 2 steps (folded into the chain-barrier
// tid0 slot; monotone mtDone skips re-polls).
// Protocol mechanics R8-verbatim: sc0/sc1 h write-through + bulk sc loads,
// vmcnt(0) + WG barrier before arrival add, tid0 poll + s_sleep.
template<bool F32>
__device__ __forceinline__ void rec_body(
    const void* __restrict__ Whh,
    const float* __restrict__ xgp,   // [2][256][4][32][16][4][8] fp32 (biases folded)
    float* __restrict__ hT,          // [8 chain][2 parity][512 k][8 b] fp32
    int* __restrict__ bar,
    int* __restrict__ xgr,
    void* __restrict__ out, int d, int bg8, int wgc,
    float* __restrict__ w_lds,       // [512][64] XOR-swizzled, 128 KB
    float* __restrict__ h_lds,       // [512][HS2]
    float* __restrict__ gbuf)        // [512] = [hcl][g][b]
{
    const int tid = threadIdx.x;
    const int kg = tid & 7;           // k-split (lane bits 0..2)
    const int bq = (tid >> 3) & 1;    // batch quad (0: b0-3, 1: b4-7)
    const int cq = tid >> 4;          // col quad (0..15): LDS cols cq*4..+3

    // ---- stage Whh once, XOR-swizzled: col c = hcl*4+g <-> gatecol =
    //      g*512 + wgc*16 + hcl. byte(k,c) = (k*256 + c*4) ^ ((k&7)<<4) ----
    {
        const int c  = tid & 63;
        const int kq = tid >> 6;
        const int gcol = (c & 3)*512 + wgc*16 + (c >> 2);
        char* wb = (char*)w_lds;
        for (int k = kq*128; k < kq*128 + 128; ++k) {
            const unsigned byte = (unsigned)(k*256 + c*4) ^ ((unsigned)(k & 7) << 4);
            *(float*)(wb + byte) = ldw<F32>(Whh, (size_t)k*GG + gcol);
        }
    }

    const int ch = d*4 + bg8;
    int* barc = bar + ch*128;         // one counter per chain, 512 B apart
    int* xrd  = xgr + d*128;          // per-dir ready counters
    float* hTc = hT + (size_t)ch * 8192;   // [2][512][8]

    float cr = 0.0f;                  // cell state (gate threads tid<128)
    const int ghcl = tid >> 3;        // gate thread: local h-col (valid tid<128)
    const int gb   = tid & 7;         // gate thread: batch (octet-local)

    // MAC read bases
    const char* wpB = (const char*)w_lds + kg*256 + ((unsigned)(cq*16) ^ ((unsigned)kg << 4));
    const float* hp = h_lds + kg*HS2 + bq*4;

    int mtDone = 1;                   // mt 0 confirmed by the entry poll below
    if (tid == 0) {
        while (__hip_atomic_load(&xrd[0], __ATOMIC_RELAXED, __HIP_MEMORY_SCOPE_AGENT) < 32)
            __builtin_amdgcn_s_sleep(1);
    }
    __syncthreads();

    for (int t = 0; t < TT; ++t) {
        const int parity = t & 1;
        const float4* hprev4 = (const float4*)(hTc + (parity ^ 1) * 4096);
        float*        hnext  = hTc + parity * 4096;

        // ---- prefetch xg (ready-gated; plain cached loads fill from L3) ----
        float xgv[4] = {0.f, 0.f, 0.f, 0.f};
        if (tid < 128) {
            const float* xgs = xgp + (((size_t)d*TT + t)*65536)
                             + (size_t)bg8*16384 + (size_t)wgc*512;
            #pragma unroll
            for (int g = 0; g < 4; ++g)
                xgv[g] = xgs[(ghcl*4 + g)*8 + gb];
        }

        // ---- stage chain h -> LDS via sc loads, single drain (16 KB) ----
        float4 hstg[4];
        #pragma unroll
        for (int i = 0; i < 4; ++i)
            hstg[i] = ld_b128_sc(hprev4 + i*256 + tid);
        asm volatile("s_waitcnt vmcnt(0)" ::: "memory");
        __builtin_amdgcn_sched_barrier(0);
        #pragma unroll
        for (int i = 0; i < 4; ++i) {
            const int idx = i*256 + tid;
            const int k  = idx >> 1;
            const int b4 = idx & 1;
            *(float4*)&h_lds[k*HS2 + b4*4] = hstg[i];
        }
        __syncthreads();

        // ---- MAC: acc[ci][bi] over k = kk*8 + kg ----
        float acc[4][4];
        #pragma unroll
        for (int i = 0; i < 4; ++i)
            #pragma unroll
            for (int j = 0; j < 4; ++j) acc[i][j] = 0.0f;
        #pragma unroll 8
        for (int kk = 0; kk < 64; ++kk) {
            const float4 wv = *(const float4*)(wpB + kk*2048);
            const float4 hv = *(const float4*)(hp + kk*(8*HS2));
            acc[0][0] += wv.x*hv.x; acc[0][1] += wv.x*hv.y; acc[0][2] += wv.x*hv.z; acc[0][3] += wv.x*hv.w;
            acc[1][0] += wv.y*hv.x; acc[1][1] += wv.y*hv.y; acc[1][2] += wv.y*hv.z; acc[1][3] += wv.y*hv.w;
            acc[2][0] += wv.z*hv.x; acc[2][1] += wv.z*hv.y; acc[2][2] += wv.z*hv.z; acc[2][3] += wv.z*hv.w;
            acc[3][0] += wv.w*hv.x; acc[3][1] += wv.w*hv.y; acc[3][2] += wv.w*hv.z; acc[3][3] += wv.w*hv.w;
        }

        // ---- reduce k-partials across kg (lane bits 0..2) ----
        #pragma unroll
        for (int i = 0; i < 4; ++i)
            #pragma unroll
            for (int j = 0; j < 4; ++j) {
                float v = acc[i][j];
                v += __shfl_xor(v, 1);
                v += __shfl_xor(v, 2);
                v += __shfl_xor(v, 4);
                acc[i][j] = v;
            }
        if (kg < 4) {
            const int ci = kg;
            *(float4*)&gbuf[(cq*4 + ci)*8 + bq*4] =
                make_float4(acc[ci][0], acc[ci][1], acc[ci][2], acc[ci][3]);
        }
        __syncthreads();

        // ---- gate combine: 128 threads, one (hcl, b) each ----
        if (tid < 128) {
            const float gi = gbuf[(ghcl*4 + 0)*8 + gb] + xgv[0];
            const float gf = gbuf[(ghcl*4 + 1)*8 + gb] + xgv[1];
            const float gc = gbuf[(ghcl*4 + 2)*8 + gb] + xgv[2];
            const float go = gbuf[(ghcl*4 + 3)*8 + gb] + xgv[3];
            const float cn = sigm(gf)*cr + sigm(gi)*tanhf(gc);
            cr = cn;
            const float hv = sigm(go)*tanhf(cn);
            const int hc = wgc*16 + ghcl;               // global h-col
            st_b32_sc(hnext + (size_t)hc*8 + gb, hv);   // write-through to L3
            const int bglob = bg8*8 + gb;
            const size_t oi = ((size_t)bglob*TT + t)*(2*HH) + (size_t)d*HH + hc;
            if constexpr (F32) ((float*)out)[oi] = hv;
            else               ((u16*)out)[oi]   = f2bf(hv);
        }

        // ---- chain barrier + xg-ready gate: drain, WG barrier, tid0 polls ----
        asm volatile("s_waitcnt vmcnt(0)" ::: "memory");
        __syncthreads();
        if (tid == 0) {
            __hip_atomic_fetch_add(barc, 1, __ATOMIC_RELAXED, __HIP_MEMORY_SCOPE_AGENT);
            const int tgt = 32 * (t + 1);
            while (__hip_atomic_load(barc, __ATOMIC_RELAXED, __HIP_MEMORY_SCOPE_AGENT) < tgt)
                __builtin_amdgcn_s_sleep(1);
            const int mtn = (t + 1) >> 1;
            if (mtn >= mtDone && mtn < 128) {
                while (__hip_atomic_load(&xrd[mtn], __ATOMIC_RELAXED, __HIP_MEMORY_SCOPE_AGENT) < 32)
                    __builtin_amdgcn_s_sleep(1);
                mtDone = mtn + 1;
            }
        }
        __syncthreads();
    }
}

__global__ __launch_bounds__(256, 1) void lstm_rec(
    const void* __restrict__ WhhF, const void* __restrict__ WhhB,
    const float* __restrict__ xgp, float* __restrict__ hT,
    int* __restrict__ bar, int* __restrict__ xgr,
    const int* __restrict__ flag, void* __restrict__ out)
{
    __shared__ float w_lds[512 * 64];    // 128 KB (XOR-swizzled)
    __shared__ float h_lds[512 * HS2];   //  24 KB
    __shared__ float gbuf[512];          //   2 KB
    const int wg  = blockIdx.x;
    const int d   = wg >> 7;
    const int r   = wg & 127;
    const int bg8 = r >> 5;
    const int wgc = r & 31;
    const void* Whh = d ? WhhB : WhhF;
    if (*flag) rec_body<true >(Whh, xgp, hT, bar, xgr, out, d, bg8, wgc, w_lds, h_lds, gbuf);
    else       rec_body<false>(Whh, xgp, hT, bar, xgr, out, d, bg8, wgc, w_lds, h_lds, gbuf);
}

// ---------------- fallback: proven round-3/4 per-step kernel ----------------
template<bool F32>
__device__ __forceinline__ void step_body(
    const void* __restrict__ x,
    const void* __restrict__ Wih, const void* __restrict__ bih,
    const void* __restrict__ Whh, const void* __restrict__ bhh,
    const float* __restrict__ h_prev, float* __restrict__ h_next,
    float* __restrict__ c_st, void* __restrict__ out,
    int d, int nblk, int t, int t_src, float* __restrict__ gbuf)
{
    const int tid = threadIdx.x;
    const int c0  = tid & 15;
    const int g   = c0 >> 2;
    const int nl  = c0 & 3;
    const int bq  = tid >> 4;
    const int col = g*512 + nblk*4 + nl;
    const int b0 = bq*2, b1 = b0 + 1;

    float p00=0.f,p01=0.f,p02=0.f,p03=0.f;
    float p10=0.f,p11=0.f,p12=0.f,p13=0.f;
    {
        const size_t xo0 = ((size_t)b0*TT + t_src) * EE;
        const size_t xo1 = ((size_t)b1*TT + t_src) * EE;
        #pragma unroll 4
        for (int k = 0; k < EE; k += 4) {
            const size_t wi = (size_t)k*GG + col;
            float w0 = ldw<F32>(Wih, wi);
            float w1 = ldw<F32>(Wih, wi +   (size_t)GG);
            float w2 = ldw<F32>(Wih, wi + 2*(size_t)GG);
            float w3 = ldw<F32>(Wih, wi + 3*(size_t)GG);
            float4 a0 = ld4<F32>(x, xo0 + k);
            float4 a1 = ld4<F32>(x, xo1 + k);
            p00 += w0*a0.x; p01 += w1*a0.y; p02 += w2*a0.z; p03 += w3*a0.w;
            p10 += w0*a1.x; p11 += w1*a1.y; p12 += w2*a1.z; p13 += w3*a1.w;
        }
    }
    {
        const float* hr0 = h_prev + (size_t)b0*HH;
        const float* hr1 = h_prev + (size_t)b1*HH;
        #pragma unroll 4
        for (int k = 0; k < HH; k += 4) {
            const size_t wi = (size_t)k*GG + col;
            float w0 = ldw<F32>(Whh, wi);
            float w1 = ldw<F32>(Whh, wi +   (size_t)GG);
            float w2 = ldw<F32>(Whh, wi + 2*(size_t)GG);
            float w3 = ldw<F32>(Whh, wi + 3*(size_t)GG);
            float4 v0 = *(const float4*)(hr0 + k);
            float4 v1 = *(const float4*)(hr1 + k);
            p00 += w0*v0.x; p01 += w1*v0.y; p02 += w2*v0.z; p03 += w3*v0.w;
            p10 += w0*v1.x; p11 += w1*v1.y; p12 += w2*v1.z; p13 += w3*v1.w;
        }
    }
    const float bias = ldw<F32>(bih, col) + ldw<F32>(bhh, col);
    gbuf[tid*2 + 0] = p00 + p01 + p02 + p03 + bias;
    gbuf[tid*2 + 1] = p10 + p11 + p12 + p13 + bias;
    __syncthreads();
    if (c0 < 4) {
        const int nlc = c0;
        const int ng  = nblk*4 + nlc;
        #pragma unroll
        for (int bi = 0; bi < 2; ++bi) {
            const int b = bq*2 + bi;
            const float gi = gbuf[(bq*16 + 0  + nlc)*2 + bi];
            const float gf = gbuf[(bq*16 + 4  + nlc)*2 + bi];
            const float gc = gbuf[(bq*16 + 8  + nlc)*2 + bi];
            const float go = gbuf[(bq*16 + 12 + nlc)*2 + bi];
            const size_t ci = (size_t)b*HH + ng;
            const float cp = c_st[ci];
            const float cn = sigm(gf)*cp + sigm(gi)*tanhf(gc);
            c_st[ci] = cn;
            const float hv = sigm(go)*tanhf(cn);
            h_next[ci] = hv;
            const size_t oi = ((size_t)b*TT + t)*(2*HH) + (size_t)d*HH + ng;
            if constexpr (F32) ((float*)out)[oi] = hv;
            else               ((u16*)out)[oi]   = f2bf(hv);
        }
    }
}

__global__ __launch_bounds__(256) void lstm_step(
    const void* __restrict__ x,
    const void* __restrict__ WihF, const void* __restrict__ bihF,
    const void* __restrict__ WhhF, const void* __restrict__ bhhF,
    const void* __restrict__ WihB, const void* __restrict__ bihB,
    const void* __restrict__ WhhB, const void* __restrict__ bhhB,
    float* __restrict__ h_buf, float* __restrict__ c_buf,
    const int* __restrict__ flag, void* __restrict__ out, int t)
{
    __shared__ float gbuf[512];
    const int bid  = blockIdx.x;
    const int d    = bid >> 7;
    const int nblk = bid & 127;
    const void* Wih = d ? WihB : WihF;
    const void* Whh = d ? WhhB : WhhF;
    const void* bih = d ? bihB : bihF;
    const void* bhh = d ? bhhB : bhhF;
    const int t_src  = d ? (TT - 1 - t) : t;
    const int parity = t & 1;
    const float* h_prev = h_buf + ((size_t)(d*2 + (parity ^ 1))) * BB * HH;
    float*       h_next = h_buf + ((size_t)(d*2 + parity)) * BB * HH;
    float*       c_st   = c_buf + (size_t)d * BB * HH;
    if (*flag) step_body<true >(x, Wih, bih, Whh, bhh, h_prev, h_next, c_st, out, d, nblk, t, t_src, gbuf);
    else       step_body<false>(x, Wih, bih, Whh, bhh, h_prev, h_next, c_st, out, d, nblk, t, t_src, gbuf);
}

// ---------------- host ----------------
extern "C" void kernel_launch(void* const* d_in, const int* in_sizes, int n_in,
                              void* d_out, int out_size, void* d_ws, size_t ws_size,
                              hipStream_t stream) {
    const void* x    = d_in[0];
    const void* WihF = d_in[1];
    const void* bihF = d_in[2];
    const void* WhhF = d_in[3];
    const void* bhhF = d_in[4];
    const void* WihB = d_in[5];
    const void* bihB = d_in[6];
    const void* WhhB = d_in[7];
    const void* bhhB = d_in[8];

    float* ws = (float*)d_ws;

    // layout (floats): xg[33554432] | h[65536] | c[32768] | bar[2048 ints] | flag
    const size_t off_xg = 0;
    const size_t off_h  = (size_t)2*TT*BB*GG;            // 33554432
    const size_t off_c  = off_h + (size_t)2*2*BB*HH;     // + 65536
    const size_t off_b  = off_c + (size_t)2*BB*HH;       // + 32768
    const size_t off_f  = off_b + 2048;
    const size_t need_bytes = (off_f + 16) * sizeof(float);

    if (ws_size >= need_bytes) {
        float* xgp  = ws + off_xg;
        float* hT   = ws + off_h;     // [8 chain][2 parity][512 k][8 b]
        float* cbuf = ws + off_c;     // unused by fast path (zeroed anyway)
        int*   bar  = (int*)(ws + off_b);
        int*   xgr  = bar + 1536;     // 256 ready counters (2 dirs x 128 mt)
        int*   flag = (int*)(ws + off_f);

        init_state<<<64, 256, 0, stream>>>((const u16*)bihF, hT, cbuf, bar, flag);
        xg_gemm<<<8192, 256, 0, stream>>>(x, WihF, bihF, bhhF, WihB, bihB, bhhB, xgp, flag, xgr);
        lstm_rec<<<256, 256, 0, stream>>>(WhhF, WhhB, xgp, hT, bar, xgr, flag, d_out);
    } else {
        float* h_buf = ws;
        float* c_buf = ws + (size_t)2*2*BB*HH;
        int*   bar   = (int*)(c_buf + (size_t)2*BB*HH);
        int*   flag  = (int*)(bar + 1024);
        init_state<<<64, 256, 0, stream>>>((const u16*)bihF, h_buf, c_buf, bar, flag);
        for (int t = 0; t < TT; ++t) {
            lstm_step<<<256, 256, 0, stream>>>(x, WihF, bihF, WhhF, bhhF,
                                               WihB, bihB, WhhB, bhhB,
                                               h_buf, c_buf, flag, d_out, t);
        }
    }
}